// Round 10
// baseline (362.885 us; speedup 1.0000x reference)
//
#include <hip/hip_runtime.h>

// B=2, C=512, GROUPS=32, H=W=64, N=4096. Attention materialized:
// fused QKV projection GEMM -> S-GEMM (BK=32) with fused exp epilogue
// (unnormalized softmax + atomic row sums l) -> PV GEMM (128x128, 4-way
// K-split, bf16 partials) -> combine4 * (1/l) -> O-proj + residual.
// Batch-merged when ws_size >= 96 MB; per-batch fallback otherwise.

typedef __attribute__((ext_vector_type(8))) short bf16x8;
typedef __attribute__((ext_vector_type(4))) float f32x4;
typedef unsigned short u16;
typedef unsigned int u32;

__device__ __forceinline__ u16 f2bf(float f) {
  u32 u = __builtin_bit_cast(u32, f);
  return (u16)((u + 0x7FFFu + ((u >> 16) & 1u)) >> 16);
}
__device__ __forceinline__ float bf2f(u16 u) {
  return __builtin_bit_cast(float, (u32)u << 16);
}
__device__ __forceinline__ void gll16(const void* g, void* l) {
  __builtin_amdgcn_global_load_lds((const __attribute__((address_space(1))) u32*)g,
                                   (__attribute__((address_space(3))) u32*)l, 16, 0, 0);
}

// ---------------- GroupNorm: stats (atomic partial) + apply ----------------
__global__ __launch_bounds__(256) void gn_stats(const float* __restrict__ x,
                                                float* __restrict__ stats) {
  int bg = blockIdx.x >> 3, slice = blockIdx.x & 7;
  const float4* xp = (const float4*)(x + (size_t)bg * 65536 + slice * 8192);
  int t = threadIdx.x;
  float s = 0.f, ss = 0.f;
  for (int i = t; i < 2048; i += 256) {
    float4 v = xp[i];
    s += v.x + v.y + v.z + v.w;
    ss += v.x * v.x + v.y * v.y + v.z * v.z + v.w * v.w;
  }
  for (int off = 32; off > 0; off >>= 1) {
    s += __shfl_down(s, off);
    ss += __shfl_down(ss, off);
  }
  __shared__ float rs[4], rss[4];
  if ((t & 63) == 0) { rs[t >> 6] = s; rss[t >> 6] = ss; }
  __syncthreads();
  if (t == 0) {
    atomicAdd(&stats[bg * 2 + 0], rs[0] + rs[1] + rs[2] + rs[3]);
    atomicAdd(&stats[bg * 2 + 1], rss[0] + rss[1] + rss[2] + rss[3]);
  }
}

__global__ __launch_bounds__(256) void gn_apply(
    const float* __restrict__ x, const float* __restrict__ w,
    const float* __restrict__ b, const float* __restrict__ stats,
    u16* __restrict__ ht) {
  int bg = blockIdx.x >> 3, slice = blockIdx.x & 7;
  int batch = bg >> 5, g = bg & 31;
  const float* xp = x + (size_t)bg * 65536;
  float mean = stats[bg * 2 + 0] * (1.f / 65536.f);
  float var = stats[bg * 2 + 1] * (1.f / 65536.f) - mean * mean;
  float rstd = rsqrtf(var + 1e-6f);
  float wsc[16], bsc[16];
#pragma unroll
  for (int cc = 0; cc < 16; ++cc) {
    float wv = w[g * 16 + cc];
    wsc[cc] = wv * rstd;
    bsc[cc] = b[g * 16 + cc] - mean * wsc[cc];
  }
  u16* hp = ht + (size_t)batch * 4096 * 512 + g * 16;
  int t = threadIdx.x;
  for (int n = slice * 512 + t; n < slice * 512 + 512; n += 256) {
    union { u16 pk[16]; uint4 v4[2]; } u;
#pragma unroll
    for (int cc = 0; cc < 16; ++cc)
      u.pk[cc] = f2bf(xp[cc * 4096 + n] * wsc[cc] + bsc[cc]);
    uint4* dst = (uint4*)(hp + (size_t)n * 512);
    dst[0] = u.v4[0];
    dst[1] = u.v4[1];
  }
}

// ---- weight/bias fp32 -> bf16 (+ zero GN stats and softmax row-sums l) ----
__global__ __launch_bounds__(256) void wcvt_kernel(
    const float* __restrict__ wq, const float* __restrict__ wk,
    const float* __restrict__ wv, const float* __restrict__ wo,
    const float* __restrict__ bq, const float* __restrict__ bk,
    u16* __restrict__ Wqk, u16* __restrict__ Wv, u16* __restrict__ Wo,
    float* __restrict__ Bqk, float* __restrict__ stats,
    float* __restrict__ lsum) {
  int i = blockIdx.x * 256 + threadIdx.x;
  Wqk[i] = f2bf(wq[i]);
  Wqk[262144 + i] = f2bf(wk[i]);
  Wv[i] = f2bf(wv[i]);
  Wo[i] = f2bf(wo[i]);
  if (i < 512) { Bqk[i] = bq[i]; Bqk[512 + i] = bk[i]; }
  if (i < 128) stats[i] = 0.f;
  if (i < 8192) lsum[i] = 0.f;
}

// ---------------- TN MFMA GEMM, BM x BN tile, BK K-chunk, runtime K --------
// D[m][n] = sum_k A[m][k]*B[n][k]; 4 waves in 2x2; wave tile (BM/2)x(BN/2).
// blockIdx.z: MODE 5 -> (batch = z>>2, ksplit = z&3); else batch = z.
// zsA/zsB/zsO: per-batch element strides on A/B/out.
// MODE 2: fp32 out at ((n>>12)*512+m)*4096+(n&4095) + bias[m] + res.
// MODE 3: bf16 out * scale. MODE 4: bf16 out.
// MODE 5: bf16 partial to {out,p1,p2,p3}[ksplit], k range [ksplit*K, +K).
// MODE 6: bf16 out = exp(v*scale); atomicAdd row sums into lsum[zb*4096+m].
// MODE 7: fused QKV projection, 1D grid of 768: blocks 0-511 compute
//         QKt[m][n]=ht.Wqk^T+Bqk[n]; blocks 512-767 compute
//         Vg[m][n]=Wv.ht^T+bv[m] (Wv via p2, bv via res, Vg via p1).
template <int BM, int BN, int BK, int MODE>
__global__ __launch_bounds__(256) void mfma_gemm(
    const u16* __restrict__ A, int sA, const u16* __restrict__ B, int sB,
    int K, const float* __restrict__ bias, const float* __restrict__ res,
    void* __restrict__ out, int ostr, float scale,
    u16* __restrict__ p1, u16* __restrict__ p2, u16* __restrict__ p3,
    size_t zsA, size_t zsB, size_t zsO, float* __restrict__ lsum) {
  constexpr int TM = BM / 32, TN = BN / 32;
  constexpr int SIA = BM * BK / 2048, SIB = BN * BK / 2048;  // wave-loads
  constexpr int KSTEPS = BK / 32;
  __shared__ char sm[(BM + BN) * BK * 2];
  char* As = sm;                  // [kc(BK/8)][mBM] 16B units
  char* Bs = sm + BM * BK * 2;    // [kc][nBN]
  int t = threadIdx.x;
  int w = t >> 6, lane = t & 63, quad = lane >> 4, ln = lane & 15;
  int wm = w >> 1, wn = w & 1;
  int m0 = blockIdx.y * BM, n0 = blockIdx.x * BN;
  int zb, ksplit;
  if (MODE == 5) { zb = blockIdx.z >> 2; ksplit = blockIdx.z & 3; }
  else           { zb = blockIdx.z;      ksplit = 0; }
  const u16* Ab;
  const u16* Bb;
  int sAe = sA, sBe = sB;
  bool qkPath = true;
  if (MODE == 7) {
    int bid = blockIdx.x;
    if (bid < 512) {            // QK projection: A=ht, B=Wqk
      Ab = A; Bb = B;
      m0 = (bid >> 3) * 128; n0 = (bid & 7) * 128;
    } else {                    // V projection: A=Wv (p2), B=ht
      qkPath = false;
      int b2 = bid - 512;
      Ab = p2; sAe = 512; Bb = A; sBe = sA;
      m0 = (b2 >> 6) * 128; n0 = (b2 & 63) * 128;
    }
  } else {
    Ab = A + (size_t)zb * zsA;
    Bb = B + (size_t)zb * zsB;
  }
  int kbase = ksplit * K;
  f32x4 acc[TM][TN] = {};

  for (int k0 = 0; k0 < K; k0 += BK) {
#pragma unroll
    for (int si = 0; si < SIA; ++si) {
      int s = (w * SIA + si) * 64 + lane;
      gll16(Ab + (size_t)(m0 + (s & (BM - 1))) * sAe + kbase + k0 + (s / BM) * 8,
            As + (w * SIA + si) * 1024);
    }
#pragma unroll
    for (int si = 0; si < SIB; ++si) {
      int s = (w * SIB + si) * 64 + lane;
      gll16(Bb + (size_t)(n0 + (s & (BN - 1))) * sBe + kbase + k0 + (s / BN) * 8,
            Bs + (w * SIB + si) * 1024);
    }
    __syncthreads();
#pragma unroll
    for (int ks = 0; ks < KSTEPS; ++ks) {
      bf16x8 af[TM], bfr[TN];
#pragma unroll
      for (int tm = 0; tm < TM; ++tm)
        af[tm] = *(const bf16x8*)(As + (((ks * 4 + quad) * BM) + wm * (BM / 2) + tm * 16 + ln) * 16);
#pragma unroll
      for (int tn = 0; tn < TN; ++tn)
        bfr[tn] = *(const bf16x8*)(Bs + (((ks * 4 + quad) * BN) + wn * (BN / 2) + tn * 16 + ln) * 16);
#pragma unroll
      for (int tm = 0; tm < TM; ++tm)
#pragma unroll
        for (int tn = 0; tn < TN; ++tn)
          acc[tm][tn] = __builtin_amdgcn_mfma_f32_16x16x32_bf16(af[tm], bfr[tn], acc[tm][tn], 0, 0, 0);
    }
    __syncthreads();
  }

  u16* pdst = nullptr;
  if (MODE == 5) {
    pdst = (ksplit == 0) ? (u16*)out : (ksplit == 1) ? p1
         : (ksplit == 2) ? p2 : p3;
    pdst += (size_t)zb * zsO;
  } else if (MODE == 7) {
    pdst = qkPath ? (u16*)out : p1;
  } else if (MODE != 2) {
    pdst = (u16*)out + (size_t)zb * zsO;
  }

  if (MODE == 6) {
    // exp epilogue: write exp(v*scale), accumulate per-row sums.
#pragma unroll
    for (int tm = 0; tm < TM; ++tm) {
#pragma unroll
      for (int r = 0; r < 4; ++r) {
        int m = m0 + wm * (BM / 2) + tm * 16 + quad * 4 + r;
        float rsum = 0.f;
#pragma unroll
        for (int tn = 0; tn < TN; ++tn) {
          int n = n0 + wn * (BN / 2) + tn * 16 + ln;
          float e = __expf(acc[tm][tn][r] * scale);
          rsum += e;
          pdst[(size_t)m * ostr + n] = f2bf(e);
        }
#pragma unroll
        for (int d = 1; d < 16; d <<= 1) rsum += __shfl_xor(rsum, d);
        if (ln == 0) atomicAdd(&lsum[(size_t)zb * 4096 + m], rsum);
      }
    }
    return;
  }

#pragma unroll
  for (int tm = 0; tm < TM; ++tm) {
    int mb = m0 + wm * (BM / 2) + tm * 16 + quad * 4;
#pragma unroll
    for (int tn = 0; tn < TN; ++tn) {
      int n = n0 + wn * (BN / 2) + tn * 16 + ln;
#pragma unroll
      for (int r = 0; r < 4; ++r) {
        int m = mb + r;
        float v = acc[tm][tn][r];
        if (MODE == 2) {
          int bb = n >> 12, nn = n & 4095;
          size_t off = ((size_t)(bb * 512 + m)) * 4096 + nn;
          ((float*)out)[off] = v + bias[m] + res[off];
        } else if (MODE == 3) {
          pdst[(size_t)m * ostr + n] = f2bf(v * scale);
        } else if (MODE == 5 || MODE == 4) {
          pdst[(size_t)m * ostr + n] = f2bf(v);
        } else if (MODE == 7) {
          float bb = qkPath ? bias[n] : res[m];  // res carries bv for V path
          pdst[(size_t)m * (qkPath ? ostr : 8192) + n] = f2bf(v + bb);
        }
      }
    }
  }
}

// -------- exact row softmax (fallback path only), in place --------
__global__ __launch_bounds__(256) void softmax_kernel(u16* __restrict__ S) {
  u16* sp = S + (size_t)blockIdx.x * 4096;
  int t = threadIdx.x;
  int w = t >> 6;
  uint4 a = ((const uint4*)sp)[t * 2];
  uint4 b = ((const uint4*)sp)[t * 2 + 1];
  u32 words[8] = {a.x, a.y, a.z, a.w, b.x, b.y, b.z, b.w};
  float v[16];
#pragma unroll
  for (int i = 0; i < 8; ++i) {
    v[2 * i] = bf2f((u16)(words[i] & 0xFFFF));
    v[2 * i + 1] = bf2f((u16)(words[i] >> 16));
  }
  float mx = v[0];
#pragma unroll
  for (int i = 1; i < 16; ++i) mx = fmaxf(mx, v[i]);
#pragma unroll
  for (int d = 1; d < 64; d <<= 1) mx = fmaxf(mx, __shfl_xor(mx, d));
  __shared__ float red[8];
  if ((t & 63) == 0) red[w] = mx;
  __syncthreads();
  mx = fmaxf(fmaxf(red[0], red[1]), fmaxf(red[2], red[3]));
  float sum = 0.f;
#pragma unroll
  for (int i = 0; i < 16; ++i) {
    v[i] = __expf(v[i] - mx);
    sum += v[i];
  }
#pragma unroll
  for (int d = 1; d < 64; d <<= 1) sum += __shfl_xor(sum, d);
  if ((t & 63) == 0) red[4 + w] = sum;
  __syncthreads();
  float inv = 1.f / (red[4] + red[5] + red[6] + red[7]);
#pragma unroll
  for (int i = 0; i < 8; ++i)
    words[i] = (u32)f2bf(v[2 * i] * inv) | ((u32)f2bf(v[2 * i + 1] * inv) << 16);
  ((uint4*)sp)[t * 2] = make_uint4(words[0], words[1], words[2], words[3]);
  ((uint4*)sp)[t * 2 + 1] = make_uint4(words[4], words[5], words[6], words[7]);
}

// ---------------- combine 4 bf16 K-split partials -> bf16 ----------------
// P0 aliases the destination exactly. NORM: multiply by 1/lsum[row].
template <bool NORM>
__global__ __launch_bounds__(256) void combine4_kernel(
    u16* __restrict__ P0, const u16* __restrict__ P1,
    const u16* __restrict__ P2, const u16* __restrict__ P3,
    const float* __restrict__ lsum) {
  int i = blockIdx.x * 256 + threadIdx.x;  // 8 elems each (one row, 8 cols)
  float inv = NORM ? 1.f / lsum[i >> 6] : 1.f;
  uint4 a = ((const uint4*)P0)[i];
  uint4 b = ((const uint4*)P1)[i];
  uint4 c = ((const uint4*)P2)[i];
  uint4 d = ((const uint4*)P3)[i];
  u32 wa[4] = {a.x, a.y, a.z, a.w}, wb[4] = {b.x, b.y, b.z, b.w};
  u32 wc[4] = {c.x, c.y, c.z, c.w}, wd[4] = {d.x, d.y, d.z, d.w};
  u32 wo_[4];
#pragma unroll
  for (int q = 0; q < 4; ++q) {
    float lo = bf2f((u16)(wa[q] & 0xFFFF)) + bf2f((u16)(wb[q] & 0xFFFF)) +
               bf2f((u16)(wc[q] & 0xFFFF)) + bf2f((u16)(wd[q] & 0xFFFF));
    float hi = bf2f((u16)(wa[q] >> 16)) + bf2f((u16)(wb[q] >> 16)) +
               bf2f((u16)(wc[q] >> 16)) + bf2f((u16)(wd[q] >> 16));
    wo_[q] = (u32)f2bf(lo * inv) | ((u32)f2bf(hi * inv) << 16);
  }
  ((uint4*)P0)[i] = make_uint4(wo_[0], wo_[1], wo_[2], wo_[3]);
}

// ---------------------------------------------------------------------------
extern "C" void kernel_launch(void* const* d_in, const int* in_sizes, int n_in,
                              void* d_out, int out_size, void* d_ws, size_t ws_size,
                              hipStream_t stream) {
  (void)in_sizes; (void)n_in; (void)out_size;
  const float* x = (const float*)d_in[0];
  const float* gnw = (const float*)d_in[1];
  const float* gnb = (const float*)d_in[2];
  const float* wq = (const float*)d_in[3];
  const float* bq = (const float*)d_in[4];
  const float* wk = (const float*)d_in[5];
  const float* bk = (const float*)d_in[6];
  const float* wv = (const float*)d_in[7];
  const float* bv = (const float*)d_in[8];
  const float* wo = (const float*)d_in[9];
  const float* bo = (const float*)d_in[10];
  float* out = (float*)d_out;

  const bool BIG = ws_size >= (size_t)96 * 1024 * 1024;
  char* ws = (char*)d_ws;
  u16* ht  = (u16*)(ws);                  // 8 MB, aliased by AOt
  u16* AOt = (u16*)(ws);
  u16* QKt = (u16*)(ws + 8388608);        // 16 MB (dead after S-GEMM -> partials)
  u16* S   = (u16*)(ws + 25165824);       // 32 MB (small) / 64 MB (big)
  size_t woff = BIG ? 92274688u : 58720256u;
  u16* Wqk = (u16*)(ws + woff);                // 1 MB
  u16* Wv  = (u16*)(ws + woff + 1048576);      // 0.5 MB
  u16* Wo  = (u16*)(ws + woff + 1572864);      // 0.5 MB
  float* stats = (float*)(ws + woff + 2097152);  // 512 B
  float* Bqk   = (float*)(ws + woff + 2097664);  // 4 KB
  float* lsum  = (float*)(ws + woff + 2101760);  // 32 KB
  // scratch inside d_out (dead before final GEMM rewrites it)
  u16* Vg  = (u16*)d_out;                       // 8 MB [512][8192]
  u16* P1g = (u16*)((char*)d_out + 8388608);    // up to 8 MB bf16 partial

  wcvt_kernel<<<1024, 256, 0, stream>>>(wq, wk, wv, wo, bq, bk, Wqk, Wv, Wo,
                                        Bqk, stats, lsum);
  gn_stats<<<512, 256, 0, stream>>>(x, stats);
  gn_apply<<<512, 256, 0, stream>>>(x, gnw, gnb, stats, ht);
  // fused QKV projection: blocks 0-511 -> QKt [pix][1024] (+Bqk over n);
  // blocks 512-767 -> Vg [c][pix] (+bv over m).  BK=32, LDS 16 KB.
  mfma_gemm<128, 128, 32, 7><<<dim3(768), 256, 0, stream>>>(
      ht, 512, Wqk, 512, 512, Bqk, bv, QKt, 1024, 1.f,
      Vg, Wv, nullptr, 0, 0, 0, nullptr);

  if (BIG) {
    // S[b][i][j] = exp(scale * q.k) (unnormalized) + row sums -> lsum.
    // BK=32 -> LDS 16 KB -> ~2x resident blocks vs BK=64.
    mfma_gemm<128, 128, 32, 6><<<dim3(32, 32, 2), 256, 0, stream>>>(
        QKt, 1024, QKt + 512, 1024, 512, nullptr, nullptr, S, 4096,
        0.044194173824159216f, nullptr, nullptr, nullptr,
        4194304u, 4194304u, 16777216u, lsum);
    // AO[b][i][c] = Shat V^T; 4-way K-split x 2 batches (grid 1024, BK=64).
    // Partials: P0 = AOt (alias-combine), P1 in d_out, P2/P3 in dead QKt.
    mfma_gemm<128, 128, 64, 5><<<dim3(4, 32, 8), 256, 0, stream>>>(
        S, 4096, Vg, 8192, 1024, nullptr, nullptr,
        AOt, 512, 1.f, P1g, QKt, QKt + 4194304, 16777216u, 4096u, 2097152u,
        nullptr);
    combine4_kernel<true><<<2048, 256, 0, stream>>>(
        AOt, P1g, QKt, QKt + 4194304, lsum);
  } else {
    u16* P2g = (u16*)((char*)d_out + 12582912);
    for (int b = 0; b < 2; ++b) {
      const u16* Qb = QKt + (size_t)b * 4194304;
      mfma_gemm<128, 128, 32, 3><<<dim3(32, 32), 256, 0, stream>>>(
          Qb, 1024, Qb + 512, 1024, 512, nullptr, nullptr, S, 4096,
          0.044194173824159216f, nullptr, nullptr, nullptr, 0, 0, 0, nullptr);
      softmax_kernel<<<4096, 256, 0, stream>>>(S);
      u16* P0 = AOt + (size_t)b * 2097152;
      u16* P3 = QKt + (size_t)b * 4194304;
      mfma_gemm<128, 128, 64, 5><<<dim3(4, 32, 4), 256, 0, stream>>>(
          S, 4096, Vg + (size_t)b * 4096, 8192, 1024, nullptr, nullptr,
          P0, 512, 1.f, P1g, P2g, P3, 0, 0, 0, nullptr);
      combine4_kernel<false><<<1024, 256, 0, stream>>>(P0, P1g, P2g, P3,
                                                       nullptr);
    }
  }
  // out = x + Wo * AO^T + bo -> fp32 [b][c][n]  (grid 512, LDS 16 KB)
  mfma_gemm<64, 128, 64, 2><<<dim3(64, 8), 256, 0, stream>>>(
      Wo, 512, AOt, 512, 512, bo, x, out, 0, 1.f,
      nullptr, nullptr, nullptr, 0, 0, 0, nullptr);
}

// Round 11
// 347.311 us; speedup vs baseline: 1.0448x; 1.0448x over previous
//
#include <hip/hip_runtime.h>

// B=2, C=512, GROUPS=32, H=W=64, N=4096. Attention materialized:
// fused QKV projection GEMM -> S-GEMM (fused exp epilogue + atomic row sums)
// -> PV GEMM (128x128, 4-way K-split, bf16 partials) -> combine4 * (1/l)
// -> O-proj + residual. Batch-merged when ws_size >= 96 MB; fallback else.
// R11: XCD-clustered block swizzle on S-GEMM / PV / QKV-QK so each XCD's
// (id%8 residue) blocks form a compact patch with working set < 4 MB L2.

typedef __attribute__((ext_vector_type(8))) short bf16x8;
typedef __attribute__((ext_vector_type(4))) float f32x4;
typedef unsigned short u16;
typedef unsigned int u32;

__device__ __forceinline__ u16 f2bf(float f) {
  u32 u = __builtin_bit_cast(u32, f);
  return (u16)((u + 0x7FFFu + ((u >> 16) & 1u)) >> 16);
}
__device__ __forceinline__ float bf2f(u16 u) {
  return __builtin_bit_cast(float, (u32)u << 16);
}
__device__ __forceinline__ void gll16(const void* g, void* l) {
  __builtin_amdgcn_global_load_lds((const __attribute__((address_space(1))) u32*)g,
                                   (__attribute__((address_space(3))) u32*)l, 16, 0, 0);
}

// ---------------- GroupNorm: stats (atomic partial) + apply ----------------
__global__ __launch_bounds__(256) void gn_stats(const float* __restrict__ x,
                                                float* __restrict__ stats) {
  int bg = blockIdx.x >> 3, slice = blockIdx.x & 7;
  const float4* xp = (const float4*)(x + (size_t)bg * 65536 + slice * 8192);
  int t = threadIdx.x;
  float s = 0.f, ss = 0.f;
  for (int i = t; i < 2048; i += 256) {
    float4 v = xp[i];
    s += v.x + v.y + v.z + v.w;
    ss += v.x * v.x + v.y * v.y + v.z * v.z + v.w * v.w;
  }
  for (int off = 32; off > 0; off >>= 1) {
    s += __shfl_down(s, off);
    ss += __shfl_down(ss, off);
  }
  __shared__ float rs[4], rss[4];
  if ((t & 63) == 0) { rs[t >> 6] = s; rss[t >> 6] = ss; }
  __syncthreads();
  if (t == 0) {
    atomicAdd(&stats[bg * 2 + 0], rs[0] + rs[1] + rs[2] + rs[3]);
    atomicAdd(&stats[bg * 2 + 1], rss[0] + rss[1] + rss[2] + rss[3]);
  }
}

__global__ __launch_bounds__(256) void gn_apply(
    const float* __restrict__ x, const float* __restrict__ w,
    const float* __restrict__ b, const float* __restrict__ stats,
    u16* __restrict__ ht) {
  int bg = blockIdx.x >> 3, slice = blockIdx.x & 7;
  int batch = bg >> 5, g = bg & 31;
  const float* xp = x + (size_t)bg * 65536;
  float mean = stats[bg * 2 + 0] * (1.f / 65536.f);
  float var = stats[bg * 2 + 1] * (1.f / 65536.f) - mean * mean;
  float rstd = rsqrtf(var + 1e-6f);
  float wsc[16], bsc[16];
#pragma unroll
  for (int cc = 0; cc < 16; ++cc) {
    float wv = w[g * 16 + cc];
    wsc[cc] = wv * rstd;
    bsc[cc] = b[g * 16 + cc] - mean * wsc[cc];
  }
  u16* hp = ht + (size_t)batch * 4096 * 512 + g * 16;
  int t = threadIdx.x;
  for (int n = slice * 512 + t; n < slice * 512 + 512; n += 256) {
    union { u16 pk[16]; uint4 v4[2]; } u;
#pragma unroll
    for (int cc = 0; cc < 16; ++cc)
      u.pk[cc] = f2bf(xp[cc * 4096 + n] * wsc[cc] + bsc[cc]);
    uint4* dst = (uint4*)(hp + (size_t)n * 512);
    dst[0] = u.v4[0];
    dst[1] = u.v4[1];
  }
}

// ---- weight/bias fp32 -> bf16 (+ zero GN stats and softmax row-sums l) ----
__global__ __launch_bounds__(256) void wcvt_kernel(
    const float* __restrict__ wq, const float* __restrict__ wk,
    const float* __restrict__ wv, const float* __restrict__ wo,
    const float* __restrict__ bq, const float* __restrict__ bk,
    u16* __restrict__ Wqk, u16* __restrict__ Wv, u16* __restrict__ Wo,
    float* __restrict__ Bqk, float* __restrict__ stats,
    float* __restrict__ lsum) {
  int i = blockIdx.x * 256 + threadIdx.x;
  Wqk[i] = f2bf(wq[i]);
  Wqk[262144 + i] = f2bf(wk[i]);
  Wv[i] = f2bf(wv[i]);
  Wo[i] = f2bf(wo[i]);
  if (i < 512) { Bqk[i] = bq[i]; Bqk[512 + i] = bk[i]; }
  if (i < 128) stats[i] = 0.f;
  if (i < 8192) lsum[i] = 0.f;
}

// ---------------- TN MFMA GEMM, BM x BN tile, BK K-chunk, runtime K --------
// D[m][n] = sum_k A[m][k]*B[n][k]; 4 waves in 2x2; wave tile (BM/2)x(BN/2).
// blockIdx.z: MODE 5 -> (batch = z>>2, ksplit = z&3); else batch = z.
// MODE 2: fp32 out at ((n>>12)*512+m)*4096+(n&4095) + bias[m] + res.
// MODE 3: bf16 out * scale. MODE 4: bf16 out.
// MODE 5: bf16 partial to {out,p1,p2,p3}[ksplit], XCD-swizzled blocks.
// MODE 6: bf16 out = exp(v*scale) + atomic row sums; XCD-swizzled blocks.
// MODE 7: fused QKV projection, 1D grid of 768 (QK path m/n bit-swapped
//         for per-XCD A-panel reuse).
template <int BM, int BN, int BK, int MODE>
__global__ __launch_bounds__(256) void mfma_gemm(
    const u16* __restrict__ A, int sA, const u16* __restrict__ B, int sB,
    int K, const float* __restrict__ bias, const float* __restrict__ res,
    void* __restrict__ out, int ostr, float scale,
    u16* __restrict__ p1, u16* __restrict__ p2, u16* __restrict__ p3,
    size_t zsA, size_t zsB, size_t zsO, float* __restrict__ lsum) {
  constexpr int TM = BM / 32, TN = BN / 32;
  constexpr int SIA = BM * BK / 2048, SIB = BN * BK / 2048;  // wave-loads
  constexpr int KSTEPS = BK / 32;
  __shared__ char sm[(BM + BN) * BK * 2];
  char* As = sm;                  // [kc(BK/8)][mBM] 16B units
  char* Bs = sm + BM * BK * 2;    // [kc][nBN]
  int t = threadIdx.x;
  int w = t >> 6, lane = t & 63, quad = lane >> 4, ln = lane & 15;
  int wm = w >> 1, wn = w & 1;
  int zb, ksplit;
  if (MODE == 5) { zb = blockIdx.z >> 2; ksplit = blockIdx.z & 3; }
  else           { zb = blockIdx.z;      ksplit = 0; }
  int m0, n0;
  const u16* Ab;
  const u16* Bb;
  int sAe = sA, sBe = sB;
  bool qkPath = true;
  if (MODE == 7) {
    int bid = blockIdx.x;
    if (bid < 512) {            // QK projection: A=ht, B=Wqk
      Ab = A; Bb = B;
      // m varies fastest: each XCD (id%8) reuses 8 A-panels (1 MB in L2).
      m0 = (bid & 63) * 128; n0 = (bid >> 6) * 128;
    } else {                    // V projection: A=Wv (p2), B=ht
      qkPath = false;
      int b2 = bid - 512;
      Ab = p2; sAe = 512; Bb = A; sBe = sA;
      m0 = (b2 >> 6) * 128; n0 = (b2 & 63) * 128;
    }
  } else if (MODE == 6 || MODE == 5) {
    // XCD-clustered swizzle: id%8 residue (one XCD, assuming round-robin)
    // gets an 8-row x (gridDim span) patch -> per-XCD L2 set ~3 MB.
    int flat = blockIdx.x + gridDim.x * blockIdx.y;
    int xcd = flat & 7, kk = flat >> 3;
    m0 = ((xcd >> 1) * 8 + (kk & 7)) * BM;
    n0 = ((kk >> 3) * 2 + (xcd & 1)) * BN;
    Ab = A + (size_t)zb * zsA;
    Bb = B + (size_t)zb * zsB;
  } else {
    m0 = blockIdx.y * BM; n0 = blockIdx.x * BN;
    Ab = A + (size_t)zb * zsA;
    Bb = B + (size_t)zb * zsB;
  }
  int kbase = ksplit * K;
  f32x4 acc[TM][TN] = {};

  for (int k0 = 0; k0 < K; k0 += BK) {
#pragma unroll
    for (int si = 0; si < SIA; ++si) {
      int s = (w * SIA + si) * 64 + lane;
      gll16(Ab + (size_t)(m0 + (s & (BM - 1))) * sAe + kbase + k0 + (s / BM) * 8,
            As + (w * SIA + si) * 1024);
    }
#pragma unroll
    for (int si = 0; si < SIB; ++si) {
      int s = (w * SIB + si) * 64 + lane;
      gll16(Bb + (size_t)(n0 + (s & (BN - 1))) * sBe + kbase + k0 + (s / BN) * 8,
            Bs + (w * SIB + si) * 1024);
    }
    __syncthreads();
#pragma unroll
    for (int ks = 0; ks < KSTEPS; ++ks) {
      bf16x8 af[TM], bfr[TN];
#pragma unroll
      for (int tm = 0; tm < TM; ++tm)
        af[tm] = *(const bf16x8*)(As + (((ks * 4 + quad) * BM) + wm * (BM / 2) + tm * 16 + ln) * 16);
#pragma unroll
      for (int tn = 0; tn < TN; ++tn)
        bfr[tn] = *(const bf16x8*)(Bs + (((ks * 4 + quad) * BN) + wn * (BN / 2) + tn * 16 + ln) * 16);
#pragma unroll
      for (int tm = 0; tm < TM; ++tm)
#pragma unroll
        for (int tn = 0; tn < TN; ++tn)
          acc[tm][tn] = __builtin_amdgcn_mfma_f32_16x16x32_bf16(af[tm], bfr[tn], acc[tm][tn], 0, 0, 0);
    }
    __syncthreads();
  }

  u16* pdst = nullptr;
  if (MODE == 5) {
    pdst = (ksplit == 0) ? (u16*)out : (ksplit == 1) ? p1
         : (ksplit == 2) ? p2 : p3;
    pdst += (size_t)zb * zsO;
  } else if (MODE == 7) {
    pdst = qkPath ? (u16*)out : p1;
  } else if (MODE != 2) {
    pdst = (u16*)out + (size_t)zb * zsO;
  }

  if (MODE == 6) {
    // exp epilogue: write exp(v*scale), accumulate per-row sums.
#pragma unroll
    for (int tm = 0; tm < TM; ++tm) {
#pragma unroll
      for (int r = 0; r < 4; ++r) {
        int m = m0 + wm * (BM / 2) + tm * 16 + quad * 4 + r;
        float rsum = 0.f;
#pragma unroll
        for (int tn = 0; tn < TN; ++tn) {
          int n = n0 + wn * (BN / 2) + tn * 16 + ln;
          float e = __expf(acc[tm][tn][r] * scale);
          rsum += e;
          pdst[(size_t)m * ostr + n] = f2bf(e);
        }
#pragma unroll
        for (int d = 1; d < 16; d <<= 1) rsum += __shfl_xor(rsum, d);
        if (ln == 0) atomicAdd(&lsum[(size_t)zb * 4096 + m], rsum);
      }
    }
    return;
  }

#pragma unroll
  for (int tm = 0; tm < TM; ++tm) {
    int mb = m0 + wm * (BM / 2) + tm * 16 + quad * 4;
#pragma unroll
    for (int tn = 0; tn < TN; ++tn) {
      int n = n0 + wn * (BN / 2) + tn * 16 + ln;
#pragma unroll
      for (int r = 0; r < 4; ++r) {
        int m = mb + r;
        float v = acc[tm][tn][r];
        if (MODE == 2) {
          int bb = n >> 12, nn = n & 4095;
          size_t off = ((size_t)(bb * 512 + m)) * 4096 + nn;
          ((float*)out)[off] = v + bias[m] + res[off];
        } else if (MODE == 3) {
          pdst[(size_t)m * ostr + n] = f2bf(v * scale);
        } else if (MODE == 5 || MODE == 4) {
          pdst[(size_t)m * ostr + n] = f2bf(v);
        } else if (MODE == 7) {
          float bb = qkPath ? bias[n] : res[m];  // res carries bv for V path
          pdst[(size_t)m * (qkPath ? ostr : 8192) + n] = f2bf(v + bb);
        }
      }
    }
  }
}

// -------- exact row softmax (fallback path only), in place --------
__global__ __launch_bounds__(256) void softmax_kernel(u16* __restrict__ S) {
  u16* sp = S + (size_t)blockIdx.x * 4096;
  int t = threadIdx.x;
  int w = t >> 6;
  uint4 a = ((const uint4*)sp)[t * 2];
  uint4 b = ((const uint4*)sp)[t * 2 + 1];
  u32 words[8] = {a.x, a.y, a.z, a.w, b.x, b.y, b.z, b.w};
  float v[16];
#pragma unroll
  for (int i = 0; i < 8; ++i) {
    v[2 * i] = bf2f((u16)(words[i] & 0xFFFF));
    v[2 * i + 1] = bf2f((u16)(words[i] >> 16));
  }
  float mx = v[0];
#pragma unroll
  for (int i = 1; i < 16; ++i) mx = fmaxf(mx, v[i]);
#pragma unroll
  for (int d = 1; d < 64; d <<= 1) mx = fmaxf(mx, __shfl_xor(mx, d));
  __shared__ float red[8];
  if ((t & 63) == 0) red[w] = mx;
  __syncthreads();
  mx = fmaxf(fmaxf(red[0], red[1]), fmaxf(red[2], red[3]));
  float sum = 0.f;
#pragma unroll
  for (int i = 0; i < 16; ++i) {
    v[i] = __expf(v[i] - mx);
    sum += v[i];
  }
#pragma unroll
  for (int d = 1; d < 64; d <<= 1) sum += __shfl_xor(sum, d);
  if ((t & 63) == 0) red[4 + w] = sum;
  __syncthreads();
  float inv = 1.f / (red[4] + red[5] + red[6] + red[7]);
#pragma unroll
  for (int i = 0; i < 8; ++i)
    words[i] = (u32)f2bf(v[2 * i] * inv) | ((u32)f2bf(v[2 * i + 1] * inv) << 16);
  ((uint4*)sp)[t * 2] = make_uint4(words[0], words[1], words[2], words[3]);
  ((uint4*)sp)[t * 2 + 1] = make_uint4(words[4], words[5], words[6], words[7]);
}

// ---------------- combine 4 bf16 K-split partials -> bf16 ----------------
// P0 aliases the destination exactly. NORM: multiply by 1/lsum[row].
template <bool NORM>
__global__ __launch_bounds__(256) void combine4_kernel(
    u16* __restrict__ P0, const u16* __restrict__ P1,
    const u16* __restrict__ P2, const u16* __restrict__ P3,
    const float* __restrict__ lsum) {
  int i = blockIdx.x * 256 + threadIdx.x;  // 8 elems each (one row, 8 cols)
  float inv = NORM ? 1.f / lsum[i >> 6] : 1.f;
  uint4 a = ((const uint4*)P0)[i];
  uint4 b = ((const uint4*)P1)[i];
  uint4 c = ((const uint4*)P2)[i];
  uint4 d = ((const uint4*)P3)[i];
  u32 wa[4] = {a.x, a.y, a.z, a.w}, wb[4] = {b.x, b.y, b.z, b.w};
  u32 wc[4] = {c.x, c.y, c.z, c.w}, wd[4] = {d.x, d.y, d.z, d.w};
  u32 wo_[4];
#pragma unroll
  for (int q = 0; q < 4; ++q) {
    float lo = bf2f((u16)(wa[q] & 0xFFFF)) + bf2f((u16)(wb[q] & 0xFFFF)) +
               bf2f((u16)(wc[q] & 0xFFFF)) + bf2f((u16)(wd[q] & 0xFFFF));
    float hi = bf2f((u16)(wa[q] >> 16)) + bf2f((u16)(wb[q] >> 16)) +
               bf2f((u16)(wc[q] >> 16)) + bf2f((u16)(wd[q] >> 16));
    wo_[q] = (u32)f2bf(lo * inv) | ((u32)f2bf(hi * inv) << 16);
  }
  ((uint4*)P0)[i] = make_uint4(wo_[0], wo_[1], wo_[2], wo_[3]);
}

// ---------------------------------------------------------------------------
extern "C" void kernel_launch(void* const* d_in, const int* in_sizes, int n_in,
                              void* d_out, int out_size, void* d_ws, size_t ws_size,
                              hipStream_t stream) {
  (void)in_sizes; (void)n_in; (void)out_size;
  const float* x = (const float*)d_in[0];
  const float* gnw = (const float*)d_in[1];
  const float* gnb = (const float*)d_in[2];
  const float* wq = (const float*)d_in[3];
  const float* bq = (const float*)d_in[4];
  const float* wk = (const float*)d_in[5];
  const float* bk = (const float*)d_in[6];
  const float* wv = (const float*)d_in[7];
  const float* bv = (const float*)d_in[8];
  const float* wo = (const float*)d_in[9];
  const float* bo = (const float*)d_in[10];
  float* out = (float*)d_out;

  const bool BIG = ws_size >= (size_t)96 * 1024 * 1024;
  char* ws = (char*)d_ws;
  u16* ht  = (u16*)(ws);                  // 8 MB, aliased by AOt
  u16* AOt = (u16*)(ws);
  u16* QKt = (u16*)(ws + 8388608);        // 16 MB (dead after S-GEMM -> partials)
  u16* S   = (u16*)(ws + 25165824);       // 32 MB (small) / 64 MB (big)
  size_t woff = BIG ? 92274688u : 58720256u;
  u16* Wqk = (u16*)(ws + woff);                // 1 MB
  u16* Wv  = (u16*)(ws + woff + 1048576);      // 0.5 MB
  u16* Wo  = (u16*)(ws + woff + 1572864);      // 0.5 MB
  float* stats = (float*)(ws + woff + 2097152);  // 512 B
  float* Bqk   = (float*)(ws + woff + 2097664);  // 4 KB
  float* lsum  = (float*)(ws + woff + 2101760);  // 32 KB
  // scratch inside d_out (dead before final GEMM rewrites it)
  u16* Vg  = (u16*)d_out;                       // 8 MB [512][8192]
  u16* P1g = (u16*)((char*)d_out + 8388608);    // up to 8 MB bf16 partial

  wcvt_kernel<<<1024, 256, 0, stream>>>(wq, wk, wv, wo, bq, bk, Wqk, Wv, Wo,
                                        Bqk, stats, lsum);
  gn_stats<<<512, 256, 0, stream>>>(x, stats);
  gn_apply<<<512, 256, 0, stream>>>(x, gnw, gnb, stats, ht);
  // fused QKV projection: blocks 0-511 -> QKt [pix][1024] (+Bqk over n);
  // blocks 512-767 -> Vg [c][pix] (+bv over m).  BK=32, LDS 16 KB.
  mfma_gemm<128, 128, 32, 7><<<dim3(768), 256, 0, stream>>>(
      ht, 512, Wqk, 512, 512, Bqk, bv, QKt, 1024, 1.f,
      Vg, Wv, nullptr, 0, 0, 0, nullptr);

  if (BIG) {
    // S[b][i][j] = exp(scale * q.k) (unnormalized) + row sums -> lsum.
    // XCD-swizzled blocks (per-XCD L2 working set ~3 MB).
    mfma_gemm<128, 128, 32, 6><<<dim3(32, 32, 2), 256, 0, stream>>>(
        QKt, 1024, QKt + 512, 1024, 512, nullptr, nullptr, S, 4096,
        0.044194173824159216f, nullptr, nullptr, nullptr,
        4194304u, 4194304u, 16777216u, lsum);
    // AO[b][i][c] = Shat V^T; 4-way K-split x 2 batches (grid 1024, BK=64),
    // XCD-swizzled. Partials: P0 = AOt (alias-combine), P1 in d_out,
    // P2/P3 in dead QKt.
    mfma_gemm<128, 128, 64, 5><<<dim3(4, 32, 8), 256, 0, stream>>>(
        S, 4096, Vg, 8192, 1024, nullptr, nullptr,
        AOt, 512, 1.f, P1g, QKt, QKt + 4194304, 16777216u, 4096u, 2097152u,
        nullptr);
    combine4_kernel<true><<<2048, 256, 0, stream>>>(
        AOt, P1g, QKt, QKt + 4194304, lsum);
  } else {
    u16* P2g = (u16*)((char*)d_out + 12582912);
    for (int b = 0; b < 2; ++b) {
      const u16* Qb = QKt + (size_t)b * 4194304;
      mfma_gemm<128, 128, 32, 3><<<dim3(32, 32), 256, 0, stream>>>(
          Qb, 1024, Qb + 512, 1024, 512, nullptr, nullptr, S, 4096,
          0.044194173824159216f, nullptr, nullptr, nullptr, 0, 0, 0, nullptr);
      softmax_kernel<<<4096, 256, 0, stream>>>(S);
      u16* P0 = AOt + (size_t)b * 2097152;
      u16* P3 = QKt + (size_t)b * 4194304;
      mfma_gemm<128, 128, 64, 5><<<dim3(4, 32, 4), 256, 0, stream>>>(
          S, 4096, Vg + (size_t)b * 4096, 8192, 1024, nullptr, nullptr,
          P0, 512, 1.f, P1g, P2g, P3, 0, 0, 0, nullptr);
      combine4_kernel<false><<<1024, 256, 0, stream>>>(P0, P1g, P2g, P3,
                                                       nullptr);
    }
  }
  // out = x + Wo * AO^T + bo -> fp32 [b][c][n]  (grid 512, LDS 16 KB)
  mfma_gemm<64, 128, 64, 2><<<dim3(64, 8), 256, 0, stream>>>(
      Wo, 512, AOt, 512, 512, bo, x, out, 0, 1.f,
      nullptr, nullptr, nullptr, 0, 0, 0, nullptr);
}